// Round 7
// baseline (415.430 us; speedup 1.0000x reference)
//
#include <hip/hip_runtime.h>
#include <math.h>

// YOLO box decode: x[B=32, A*(NC+5)=255, G=52, G=52] f32 ->
// out[B, A*G*G=8112, 85] f32  (+ trailing scalar 0 from the tuple return).
//
// R1: TILE 64 (7 blocks/CU), float4 reads, native exp.      47.2 -> 37.6 us
// R3/R4: unrolled 6-deep load/store phases (MLP), NT stores. 37.6 -> 35.7 us
// R5: TILE=52 FAILED (38.7): 208B segments straddle shared lines, FETCH +22%.
// R6: wave-private 16-cell tiles FAILED (39.2): 64B read segments -> TA
//     request amplification. Lesson: keep 256B-aligned read segments.
// R7: R4 skeleton + 2-tile software pipeline per block. After barrier A,
//     issue tile B's 6 global loads (vmcnt FIFO: loads retire before the
//     younger NT stores, so counted waitcnt won't serialize), then flush
//     tile A. B's HBM latency hides under A's LDS-read+store; A's stores
//     drain under B's transform. One 21.76KB LDS buffer reused.

#define NB    32
#define NA    3
#define NCH   85
#define GG    52
#define CELLS (GG * GG)          // 2704
#define TILE  64
#define PAIR  (2 * TILE)         // 128 cells per block
#define NPAIR ((CELLS + PAIR - 1) / PAIR)   // 22 (block 21: A=16 cells, B=0)
#define STRIDEF 8.0f

typedef float f32x4 __attribute__((ext_vector_type(4)));

__device__ __forceinline__ float sigm(float v) {
    return __fdividef(1.0f, 1.0f + __expf(-v));
}

struct Frag { f32x4 v[6]; };

__device__ __forceinline__ void issue_loads(const float* __restrict__ xb,
                                            int start, int c4, bool act, Frag& f) {
    if (!act) return;
    #pragma unroll
    for (int k = 0; k < 5; ++k)
        f.v[k] = *(const f32x4*)(xb + (size_t)(start + 16 * k) * CELLS + c4);
    if (start < 5)
        f.v[5] = *(const f32x4*)(xb + (size_t)(start + 80) * CELLS + c4);
}

__device__ __forceinline__ void xform_write(const Frag& f, int start, int c4,
                                            int cell0, float aw, float ah,
                                            float* __restrict__ ldsW, bool act) {
    if (!act) return;
    float gx[4], gy[4];
    #pragma unroll
    for (int j = 0; j < 4; ++j) {
        const int cell = cell0 + c4 + j;
        gx[j] = (float)(cell % GG);
        gy[j] = (float)(cell / GG);
    }
    {
        float r[4] = {f.v[0].x, f.v[0].y, f.v[0].z, f.v[0].w};
        if (start == 0) {
            #pragma unroll
            for (int j = 0; j < 4; ++j) r[j] = (sigm(r[j]) + gx[j]) * STRIDEF;
        } else if (start == 1) {
            #pragma unroll
            for (int j = 0; j < 4; ++j) r[j] = (sigm(r[j]) + gy[j]) * STRIDEF;
        } else if (start == 2) {
            #pragma unroll
            for (int j = 0; j < 4; ++j) r[j] = __expf(r[j]) * aw;
        } else if (start == 3) {
            #pragma unroll
            for (int j = 0; j < 4; ++j) r[j] = __expf(r[j]) * ah;
        } else {
            #pragma unroll
            for (int j = 0; j < 4; ++j) r[j] = sigm(r[j]);
        }
        #pragma unroll
        for (int j = 0; j < 4; ++j) ldsW[(c4 + j) * NCH + start] = r[j];
    }
    #pragma unroll
    for (int k = 1; k < 5; ++k) {
        const int ch = start + 16 * k;
        float r[4] = {f.v[k].x, f.v[k].y, f.v[k].z, f.v[k].w};
        #pragma unroll
        for (int j = 0; j < 4; ++j) ldsW[(c4 + j) * NCH + ch] = sigm(r[j]);
    }
    if (start < 5) {
        const int ch = start + 80;
        float r[4] = {f.v[5].x, f.v[5].y, f.v[5].z, f.v[5].w};
        #pragma unroll
        for (int j = 0; j < 4; ++j) ldsW[(c4 + j) * NCH + ch] = sigm(r[j]);
    }
}

__device__ __forceinline__ void flush(float* __restrict__ ob,
                                      const float* __restrict__ ldsW,
                                      int total4, int tid) {
    const f32x4* l4 = (const f32x4*)ldsW;
    f32x4* o4 = (f32x4*)ob;
    f32x4 t[6];
    #pragma unroll
    for (int k = 0; k < 6; ++k) {
        const int j = tid + 256 * k;
        if (j < total4) t[k] = l4[j];
    }
    #pragma unroll
    for (int k = 0; k < 6; ++k) {
        const int j = tid + 256 * k;
        if (j < total4) __builtin_nontemporal_store(t[k], &o4[j]);
    }
}

__global__ __launch_bounds__(256, 6) void yolo_decode(const float* __restrict__ x,
                                                      float* __restrict__ out,
                                                      long long out_size) {
    __shared__ __align__(16) float lds[TILE * NCH];   // 21.76 KB

    const int pair = blockIdx.x;
    const int a    = blockIdx.y;
    const int b    = blockIdx.z;
    const int cellA = pair * PAIR;
    const int cellB = cellA + TILE;
    const int ncA = min(TILE, CELLS - cellA);               // 64 or 16
    const int ncB = max(0, min(TILE, CELLS - cellB));       // 64 or 0

    const int tid  = threadIdx.x;
    const int lane = tid & 63;
    const int wv   = tid >> 6;

    const float aw = (a == 0) ? 10.0f : (a == 1) ? 16.0f : 33.0f;
    const float ah = (a == 0) ? 13.0f : (a == 1) ? 30.0f : 23.0f;

    // fold the tuple's trailing scalar 0 into this kernel
    const long long MAIN = (long long)NB * NA * CELLS * NCH;
    if (pair == 0 && a == 0 && b == 0 && tid == 0 && out_size > MAIN) {
        for (long long i = MAIN; i < out_size; ++i) out[i] = 0.0f;
    }

    const float* xbase = x + ((size_t)(b * NA + a) * NCH) * CELLS;
    float* obase = out + ((size_t)(b * NA + a) * CELLS) * NCH;

    const int grp   = lane >> 4;
    const int c4    = (lane & 15) * 4;                // 0..60
    const int start = wv * 4 + grp;                   // 0..15

    // ---- stage A: load + transform + LDS ----
    Frag fA;
    issue_loads(xbase + cellA, start, c4, c4 < ncA, fA);
    xform_write(fA, start, c4, cellA, aw, ah, lds, c4 < ncA);
    __syncthreads();

    // ---- issue stage B loads (in flight during A's flush) ----
    Frag fB;
    if (ncB > 0) issue_loads(xbase + cellB, start, c4, c4 < ncB, fB);

    // ---- flush A ----
    flush(obase + (size_t)cellA * NCH, lds, (ncA * NCH) >> 2, tid);

    if (ncB > 0) {
        __syncthreads();                              // A's LDS reads done
        xform_write(fB, start, c4, cellB, aw, ah, lds, c4 < ncB);
        __syncthreads();
        flush(obase + (size_t)cellB * NCH, lds, (ncB * NCH) >> 2, tid);
    }
}

extern "C" void kernel_launch(void* const* d_in, const int* in_sizes, int n_in,
                              void* d_out, int out_size, void* d_ws, size_t ws_size,
                              hipStream_t stream) {
    const float* x = (const float*)d_in[0];
    float* out = (float*)d_out;

    dim3 grid(NPAIR, NA, NB);       // 22 x 3 x 32 = 2112 blocks
    yolo_decode<<<grid, 256, 0, stream>>>(x, out, (long long)out_size);
}

// Round 8
// 164.982 us; speedup vs baseline: 2.5180x; 2.5180x over previous
//
#include <hip/hip_runtime.h>
#include <math.h>

// YOLO box decode: x[B=32, A*(NC+5)=255, G=52, G=52] f32 ->
// out[B, A*G*G=8112, 85] f32  (+ trailing scalar 0 from the tuple return).
//
// R1: TILE 64 (7 blocks/CU), float4 reads, native exp.      47.2 -> 37.6 us
// R3/R4: unrolled 6-deep load/store phases (MLP), NT stores. 37.6 -> 35.7 us
// R5: TILE=52 FAILED (38.7): 208B segments straddle shared lines, FETCH +22%.
// R6: wave-private 16-cell tiles FAILED (39.2): 64B read segments -> TA
//     request amplification. Lesson: keep 256B-aligned read segments.
// R7: 2-tile pipeline FAILED (415us): Frag&-by-ref + launch_bounds(256,6)
//     VGPR cap -> 24-reg prefetch spilled to scratch (FETCH 54->222MB).
// R8: same pipeline, spill-proofed: named f32x4 values (no struct refs),
//     launch_bounds(256,4) = 128-VGPR budget (LDS caps blocks/CU at 7
//     anyway, needing only <=73 VGPRs), zero-init prefetch regs.
//     B's HBM latency hides under A's flush; A's NT stores drain under
//     B's transform.

#define NB    32
#define NA    3
#define NCH   85
#define GG    52
#define CELLS (GG * GG)          // 2704
#define TILE  64
#define PAIR  (2 * TILE)         // 128 cells per block
#define NPAIR ((CELLS + PAIR - 1) / PAIR)   // 22 (block 21: A=16 cells, no B)
#define STRIDEF 8.0f

typedef float f32x4 __attribute__((ext_vector_type(4)));

__device__ __forceinline__ float sigm(float v) {
    return __fdividef(1.0f, 1.0f + __expf(-v));
}

// transform 6 channel-fragments (by VALUE -- keep in VGPRs) and scatter
// into LDS in output order. start: first channel 0..15; c4: local cell*4.
__device__ __forceinline__ void xform(float* __restrict__ ldsW, int start, int c4,
                                      int cell0, float aw, float ah,
                                      f32x4 v0, f32x4 v1, f32x4 v2, f32x4 v3,
                                      f32x4 v4, f32x4 v5, bool has6) {
    float gx[4], gy[4];
    #pragma unroll
    for (int j = 0; j < 4; ++j) {
        const int cell = cell0 + c4 + j;
        gx[j] = (float)(cell % GG);
        gy[j] = (float)(cell / GG);
    }
    {
        float r[4] = {v0.x, v0.y, v0.z, v0.w};
        if (start == 0) {
            #pragma unroll
            for (int j = 0; j < 4; ++j) r[j] = (sigm(r[j]) + gx[j]) * STRIDEF;
        } else if (start == 1) {
            #pragma unroll
            for (int j = 0; j < 4; ++j) r[j] = (sigm(r[j]) + gy[j]) * STRIDEF;
        } else if (start == 2) {
            #pragma unroll
            for (int j = 0; j < 4; ++j) r[j] = __expf(r[j]) * aw;
        } else if (start == 3) {
            #pragma unroll
            for (int j = 0; j < 4; ++j) r[j] = __expf(r[j]) * ah;
        } else {
            #pragma unroll
            for (int j = 0; j < 4; ++j) r[j] = sigm(r[j]);
        }
        #pragma unroll
        for (int j = 0; j < 4; ++j) ldsW[(c4 + j) * NCH + start] = r[j];
    }
    f32x4 vv[4] = {v1, v2, v3, v4};                   // static-indexed below
    #pragma unroll
    for (int k = 1; k < 5; ++k) {
        const int ch = start + 16 * k;
        const f32x4 w = vv[k - 1];
        float r[4] = {w.x, w.y, w.z, w.w};
        #pragma unroll
        for (int j = 0; j < 4; ++j) ldsW[(c4 + j) * NCH + ch] = sigm(r[j]);
    }
    if (has6) {
        const int ch = start + 80;
        float r[4] = {v5.x, v5.y, v5.z, v5.w};
        #pragma unroll
        for (int j = 0; j < 4; ++j) ldsW[(c4 + j) * NCH + ch] = sigm(r[j]);
    }
}

__global__ __launch_bounds__(256, 4) void yolo_decode(const float* __restrict__ x,
                                                      float* __restrict__ out,
                                                      long long out_size) {
    __shared__ __align__(16) float lds[TILE * NCH];   // 21.76 KB -> 7 blocks/CU

    const int pair = blockIdx.x;
    const int a    = blockIdx.y;
    const int b    = blockIdx.z;
    const int cellA = pair * PAIR;
    const int cellB = cellA + TILE;
    const int ncA  = min(TILE, CELLS - cellA);        // 64 or 16
    const bool hasB = (cellB < CELLS);                // false only for pair 21

    const int tid  = threadIdx.x;
    const int lane = tid & 63;
    const int wv   = tid >> 6;

    const float aw = (a == 0) ? 10.0f : (a == 1) ? 16.0f : 33.0f;
    const float ah = (a == 0) ? 13.0f : (a == 1) ? 30.0f : 23.0f;

    // fold the tuple's trailing scalar 0 into this kernel
    const long long MAIN = (long long)NB * NA * CELLS * NCH;
    if (pair == 0 && a == 0 && b == 0 && tid == 0 && out_size > MAIN) {
        for (long long i = MAIN; i < out_size; ++i) out[i] = 0.0f;
    }

    const float* xbase = x + ((size_t)(b * NA + a) * NCH) * CELLS;
    float* obase = out + ((size_t)(b * NA + a) * CELLS) * NCH;

    const int grp   = lane >> 4;
    const int c4    = (lane & 15) * 4;                // 0..60
    const int start = wv * 4 + grp;                   // 0..15
    const bool has6 = (start < 5);

    // ---- stage A: load + transform + LDS ----
    if (c4 < ncA) {
        const float* xb = xbase + cellA;
        f32x4 a0 = *(const f32x4*)(xb + (size_t)(start     ) * CELLS + c4);
        f32x4 a1 = *(const f32x4*)(xb + (size_t)(start + 16) * CELLS + c4);
        f32x4 a2 = *(const f32x4*)(xb + (size_t)(start + 32) * CELLS + c4);
        f32x4 a3 = *(const f32x4*)(xb + (size_t)(start + 48) * CELLS + c4);
        f32x4 a4 = *(const f32x4*)(xb + (size_t)(start + 64) * CELLS + c4);
        f32x4 a5 = a4;
        if (has6) a5 = *(const f32x4*)(xb + (size_t)(start + 80) * CELLS + c4);
        xform(lds, start, c4, cellA, aw, ah, a0, a1, a2, a3, a4, a5, has6);
    }
    __syncthreads();

    // ---- prefetch stage B (in flight during A's flush) ----
    f32x4 b0 = {}, b1 = {}, b2 = {}, b3 = {}, b4 = {}, b5 = {};
    if (hasB) {
        const float* xb = xbase + cellB;
        b0 = *(const f32x4*)(xb + (size_t)(start     ) * CELLS + c4);
        b1 = *(const f32x4*)(xb + (size_t)(start + 16) * CELLS + c4);
        b2 = *(const f32x4*)(xb + (size_t)(start + 32) * CELLS + c4);
        b3 = *(const f32x4*)(xb + (size_t)(start + 48) * CELLS + c4);
        b4 = *(const f32x4*)(xb + (size_t)(start + 64) * CELLS + c4);
        if (has6) b5 = *(const f32x4*)(xb + (size_t)(start + 80) * CELLS + c4);
    }

    // ---- flush A (batched ds_reads, then NT stores) ----
    {
        const int total4 = (ncA * NCH) >> 2;          // 1360 or 340
        const f32x4* l4 = (const f32x4*)lds;
        f32x4* o4 = (f32x4*)(obase + (size_t)cellA * NCH);
        f32x4 t[6];
        #pragma unroll
        for (int k = 0; k < 6; ++k) {
            const int j = tid + 256 * k;
            if (j < total4) t[k] = l4[j];
        }
        #pragma unroll
        for (int k = 0; k < 6; ++k) {
            const int j = tid + 256 * k;
            if (j < total4) __builtin_nontemporal_store(t[k], &o4[j]);
        }
    }

    // ---- stage B: transform + LDS + flush ----
    if (hasB) {
        __syncthreads();                              // A's LDS reads done
        xform(lds, start, c4, cellB, aw, ah, b0, b1, b2, b3, b4, b5, has6);
        __syncthreads();
        const int total4 = (TILE * NCH) >> 2;         // 1360
        const f32x4* l4 = (const f32x4*)lds;
        f32x4* o4 = (f32x4*)(obase + (size_t)cellB * NCH);
        f32x4 t[6];
        #pragma unroll
        for (int k = 0; k < 6; ++k) {
            const int j = tid + 256 * k;
            if (j < total4) t[k] = l4[j];
        }
        #pragma unroll
        for (int k = 0; k < 6; ++k) {
            const int j = tid + 256 * k;
            if (j < total4) __builtin_nontemporal_store(t[k], &o4[j]);
        }
    }
}

extern "C" void kernel_launch(void* const* d_in, const int* in_sizes, int n_in,
                              void* d_out, int out_size, void* d_ws, size_t ws_size,
                              hipStream_t stream) {
    const float* x = (const float*)d_in[0];
    float* out = (float*)d_out;

    dim3 grid(NPAIR, NA, NB);       // 22 x 3 x 32 = 2112 blocks
    yolo_decode<<<grid, 256, 0, stream>>>(x, out, (long long)out_size);
}

// Round 9
// 35.309 us; speedup vs baseline: 11.7654x; 4.6725x over previous
//
#include <hip/hip_runtime.h>
#include <math.h>

// YOLO box decode: x[B=32, A*(NC+5)=255, G=52, G=52] f32 ->
// out[B, A*G*G=8112, 85] f32  (+ trailing scalar 0 from the tuple return).
//
// R1: TILE 64 (7 blocks/CU), float4 reads, native exp.      47.2 -> 37.6 us
// R3/R4: unrolled 6-deep load/store phases (MLP), NT stores. 37.6 -> 35.7 us
// R5: TILE=52 FAILED (38.7): misaligned 208B segments, FETCH +22%.
// R6: wave-private 16-cell tiles FAILED (39.2): 64B read segments.
// R7: 2-tile pipeline FAILED (415us): struct-ref frags spilled (FETCH 222MB).
// R8: pipeline v2 FAILED (165us): peak liveness 60+ VGPR vs allocator cap 64
//     -> still spilled (FETCH 97MB, scratch W 355MB).
// R9: pipeline v3, liveness-engineered: same (256,7) envelope as good R4;
//     flush in two half-batches of 3 (12 VGPR) so peak live =
//     B-prefetch(24) + t(12) + addr ~= 50 < 64. Explicit named scalars
//     only. B loads issued after transform-A (A frags dead), in flight
//     across barrier + flush-A.

#define NB    32
#define NA    3
#define NCH   85
#define GG    52
#define CELLS (GG * GG)          // 2704
#define TILE  64
#define PAIR  (2 * TILE)         // 128 cells per block
#define NPAIR ((CELLS + PAIR - 1) / PAIR)   // 22 (pair 21: A=16 cells, no B)
#define STRIDEF 8.0f

typedef float f32x4 __attribute__((ext_vector_type(4)));

__device__ __forceinline__ float sigm(float v) {
    return __fdividef(1.0f, 1.0f + __expf(-v));
}

// transform 6 channel-fragments (by value) -> LDS in output order.
__device__ __forceinline__ void xform(float* __restrict__ ldsW, int start, int c4,
                                      int cell0, float aw, float ah,
                                      f32x4 v0, f32x4 v1, f32x4 v2, f32x4 v3,
                                      f32x4 v4, f32x4 v5, bool has6) {
    // channel 'start' (only one that can be special: start<16)
    {
        float r0 = v0.x, r1 = v0.y, r2 = v0.z, r3 = v0.w;
        if (start == 0) {
            const int cell = cell0 + c4;
            r0 = (sigm(r0) + (float)((cell    ) % GG)) * STRIDEF;
            r1 = (sigm(r1) + (float)((cell + 1) % GG)) * STRIDEF;
            r2 = (sigm(r2) + (float)((cell + 2) % GG)) * STRIDEF;
            r3 = (sigm(r3) + (float)((cell + 3) % GG)) * STRIDEF;
        } else if (start == 1) {
            const int cell = cell0 + c4;
            r0 = (sigm(r0) + (float)((cell    ) / GG)) * STRIDEF;
            r1 = (sigm(r1) + (float)((cell + 1) / GG)) * STRIDEF;
            r2 = (sigm(r2) + (float)((cell + 2) / GG)) * STRIDEF;
            r3 = (sigm(r3) + (float)((cell + 3) / GG)) * STRIDEF;
        } else if (start == 2) {
            r0 = __expf(r0) * aw; r1 = __expf(r1) * aw;
            r2 = __expf(r2) * aw; r3 = __expf(r3) * aw;
        } else if (start == 3) {
            r0 = __expf(r0) * ah; r1 = __expf(r1) * ah;
            r2 = __expf(r2) * ah; r3 = __expf(r3) * ah;
        } else {
            r0 = sigm(r0); r1 = sigm(r1); r2 = sigm(r2); r3 = sigm(r3);
        }
        ldsW[(c4    ) * NCH + start] = r0;
        ldsW[(c4 + 1) * NCH + start] = r1;
        ldsW[(c4 + 2) * NCH + start] = r2;
        ldsW[(c4 + 3) * NCH + start] = r3;
    }
    // channels start+16/32/48/64: always plain sigmoid
    {
        const int ch = start + 16;
        ldsW[(c4    ) * NCH + ch] = sigm(v1.x);
        ldsW[(c4 + 1) * NCH + ch] = sigm(v1.y);
        ldsW[(c4 + 2) * NCH + ch] = sigm(v1.z);
        ldsW[(c4 + 3) * NCH + ch] = sigm(v1.w);
    }
    {
        const int ch = start + 32;
        ldsW[(c4    ) * NCH + ch] = sigm(v2.x);
        ldsW[(c4 + 1) * NCH + ch] = sigm(v2.y);
        ldsW[(c4 + 2) * NCH + ch] = sigm(v2.z);
        ldsW[(c4 + 3) * NCH + ch] = sigm(v2.w);
    }
    {
        const int ch = start + 48;
        ldsW[(c4    ) * NCH + ch] = sigm(v3.x);
        ldsW[(c4 + 1) * NCH + ch] = sigm(v3.y);
        ldsW[(c4 + 2) * NCH + ch] = sigm(v3.z);
        ldsW[(c4 + 3) * NCH + ch] = sigm(v3.w);
    }
    {
        const int ch = start + 64;
        ldsW[(c4    ) * NCH + ch] = sigm(v4.x);
        ldsW[(c4 + 1) * NCH + ch] = sigm(v4.y);
        ldsW[(c4 + 2) * NCH + ch] = sigm(v4.z);
        ldsW[(c4 + 3) * NCH + ch] = sigm(v4.w);
    }
    if (has6) {
        const int ch = start + 80;
        ldsW[(c4    ) * NCH + ch] = sigm(v5.x);
        ldsW[(c4 + 1) * NCH + ch] = sigm(v5.y);
        ldsW[(c4 + 2) * NCH + ch] = sigm(v5.z);
        ldsW[(c4 + 3) * NCH + ch] = sigm(v5.w);
    }
}

// flush 3 float4 per thread (12 VGPR batch): rounds k0..k0+2
__device__ __forceinline__ void flush_half(const float* __restrict__ ldsW,
                                           f32x4* __restrict__ o4,
                                           int total4, int tid, int k0) {
    f32x4 t0 = {}, t1 = {}, t2 = {};
    const int j0 = tid + 256 * (k0 + 0);
    const int j1 = tid + 256 * (k0 + 1);
    const int j2 = tid + 256 * (k0 + 2);
    const f32x4* l4 = (const f32x4*)ldsW;
    if (j0 < total4) t0 = l4[j0];
    if (j1 < total4) t1 = l4[j1];
    if (j2 < total4) t2 = l4[j2];
    if (j0 < total4) __builtin_nontemporal_store(t0, &o4[j0]);
    if (j1 < total4) __builtin_nontemporal_store(t1, &o4[j1]);
    if (j2 < total4) __builtin_nontemporal_store(t2, &o4[j2]);
}

__global__ __launch_bounds__(256, 7) void yolo_decode(const float* __restrict__ x,
                                                      float* __restrict__ out,
                                                      long long out_size) {
    __shared__ __align__(16) float lds[TILE * NCH];   // 21.76 KB -> 7 blocks/CU

    const int pair = blockIdx.x;
    const int a    = blockIdx.y;
    const int b    = blockIdx.z;
    const int cellA = pair * PAIR;
    const int cellB = cellA + TILE;
    const int ncA  = min(TILE, CELLS - cellA);        // 64 or 16
    const bool hasB = (cellB < CELLS);                // false only for pair 21

    const int tid  = threadIdx.x;
    const int lane = tid & 63;
    const int wv   = tid >> 6;

    const float aw = (a == 0) ? 10.0f : (a == 1) ? 16.0f : 33.0f;
    const float ah = (a == 0) ? 13.0f : (a == 1) ? 30.0f : 23.0f;

    // fold the tuple's trailing scalar 0 into this kernel
    const long long MAIN = (long long)NB * NA * CELLS * NCH;
    if (pair == 0 && a == 0 && b == 0 && tid == 0 && out_size > MAIN) {
        for (long long i = MAIN; i < out_size; ++i) out[i] = 0.0f;
    }

    const float* xbase = x + ((size_t)(b * NA + a) * NCH) * CELLS;
    float* obase = out + ((size_t)(b * NA + a) * CELLS) * NCH;

    const int grp   = lane >> 4;
    const int c4    = (lane & 15) * 4;                // 0..60
    const int start = wv * 4 + grp;                   // 0..15
    const bool has6 = (start < 5);

    // ---- stage A: load + transform + LDS (frags die inside) ----
    if (c4 < ncA) {
        const float* xb = xbase + cellA;
        f32x4 a0 = *(const f32x4*)(xb + (size_t)(start     ) * CELLS + c4);
        f32x4 a1 = *(const f32x4*)(xb + (size_t)(start + 16) * CELLS + c4);
        f32x4 a2 = *(const f32x4*)(xb + (size_t)(start + 32) * CELLS + c4);
        f32x4 a3 = *(const f32x4*)(xb + (size_t)(start + 48) * CELLS + c4);
        f32x4 a4 = *(const f32x4*)(xb + (size_t)(start + 64) * CELLS + c4);
        f32x4 a5 = a4;
        if (has6) a5 = *(const f32x4*)(xb + (size_t)(start + 80) * CELLS + c4);
        xform(lds, start, c4, cellA, aw, ah, a0, a1, a2, a3, a4, a5, has6);
    }

    // ---- prefetch stage B: in flight across barrier + flush-A ----
    f32x4 b0 = {}, b1 = {}, b2 = {}, b3 = {}, b4 = {}, b5 = {};
    if (hasB) {
        const float* xb = xbase + cellB;
        b0 = *(const f32x4*)(xb + (size_t)(start     ) * CELLS + c4);
        b1 = *(const f32x4*)(xb + (size_t)(start + 16) * CELLS + c4);
        b2 = *(const f32x4*)(xb + (size_t)(start + 32) * CELLS + c4);
        b3 = *(const f32x4*)(xb + (size_t)(start + 48) * CELLS + c4);
        b4 = *(const f32x4*)(xb + (size_t)(start + 64) * CELLS + c4);
        if (has6) b5 = *(const f32x4*)(xb + (size_t)(start + 80) * CELLS + c4);
    }

    __syncthreads();

    // ---- flush A in two half-batches (peak live: 24 B-frag + 12 t) ----
    {
        const int total4 = (ncA * NCH) >> 2;          // 1360 or 340
        f32x4* o4 = (f32x4*)(obase + (size_t)cellA * NCH);
        flush_half(lds, o4, total4, tid, 0);
        flush_half(lds, o4, total4, tid, 3);
    }

    // ---- stage B: transform + LDS + flush ----
    if (hasB) {
        __syncthreads();                              // A's LDS reads done
        xform(lds, start, c4, cellB, aw, ah, b0, b1, b2, b3, b4, b5, has6);
        __syncthreads();
        const int total4 = (TILE * NCH) >> 2;         // 1360
        f32x4* o4 = (f32x4*)(obase + (size_t)cellB * NCH);
        flush_half(lds, o4, total4, tid, 0);
        flush_half(lds, o4, total4, tid, 3);
    }
}

extern "C" void kernel_launch(void* const* d_in, const int* in_sizes, int n_in,
                              void* d_out, int out_size, void* d_ws, size_t ws_size,
                              hipStream_t stream) {
    const float* x = (const float*)d_in[0];
    float* out = (float*)d_out;

    dim3 grid(NPAIR, NA, NB);       // 22 x 3 x 32 = 2112 blocks
    yolo_decode<<<grid, 256, 0, stream>>>(x, out, (long long)out_size);
}

// Round 10
// 33.230 us; speedup vs baseline: 12.5015x; 1.0626x over previous
//
#include <hip/hip_runtime.h>
#include <math.h>

// YOLO box decode: x[B=32, A*(NC+5)=255, G=52, G=52] f32 ->
// out[B, A*G*G=8112, 85] f32  (+ trailing scalar 0 from the tuple return).
//
// R1: TILE 64 (7 blocks/CU), float4 reads, native exp.      47.2 -> 37.6 us
// R3/R4: unrolled 6-deep load/store phases (MLP), NT stores. 37.6 -> 35.7 us
// R5: TILE=52 FAILED (38.7): misaligned 208B segments, FETCH +22%.
// R6: wave-private 16-cell tiles FAILED (39.2): 64B read segments.
// R7/R8: 2-tile pipeline FAILED (415/165us): VGPR spills to scratch.
// R9: spill-free pipeline = R4+1% (35.3us). VGPR=36 shows compiler sank the
//     prefetch -- pipeline never ran. Little's law: read MLP is ample; the
//     bottleneck is NOT load latency.
// R10: read-stream coarsening. block=512, TILE=128: each half-wave reads a
//     contiguous 512B segment (2x R4), halving DRAM stream count. No
//     pairing (was +1%, hurts tail granularity). One barrier per block.
//     LDS 43.5KB -> 3 blocks/CU = 24-wave cap; launch_bounds(512,6) caps
//     VGPR at ~85 so 3 blocks always fit.

#define NB    32
#define NA    3
#define NCH   85
#define GG    52
#define CELLS (GG * GG)          // 2704
#define TILE  128                // cells per block
#define NTILES ((CELLS + TILE - 1) / TILE)   // 22 (21 full + tail of 16)
#define STRIDEF 8.0f

typedef float f32x4 __attribute__((ext_vector_type(4)));

__device__ __forceinline__ float sigm(float v) {
    return __fdividef(1.0f, 1.0f + __expf(-v));
}

__global__ __launch_bounds__(512, 6) void yolo_decode(const float* __restrict__ x,
                                                      float* __restrict__ out,
                                                      long long out_size) {
    __shared__ __align__(16) float lds[TILE * NCH];   // 43.52 KB -> 3 blocks/CU

    const int tile = blockIdx.x;
    const int a    = blockIdx.y;
    const int b    = blockIdx.z;
    const int cell0 = tile * TILE;
    const int ncell = min(TILE, CELLS - cell0);       // 128 or 16

    const int tid  = threadIdx.x;

    const float aw = (a == 0) ? 10.0f : (a == 1) ? 16.0f : 33.0f;
    const float ah = (a == 0) ? 13.0f : (a == 1) ? 30.0f : 23.0f;

    // fold the tuple's trailing scalar 0 into this kernel
    const long long MAIN = (long long)NB * NA * CELLS * NCH;
    if (tile == 0 && a == 0 && b == 0 && tid == 0 && out_size > MAIN) {
        for (long long i = MAIN; i < out_size; ++i) out[i] = 0.0f;
    }

    const float* xb = x + ((size_t)(b * NA + a) * NCH) * CELLS + cell0;

    // 512 threads: 16 channel-groups x 32 cell-slots.
    // Each half-wave (32 lanes) reads one contiguous 512B segment per load.
    const int start = tid >> 5;                       // channel group 0..15
    const int c4    = (tid & 31) * 4;                 // local cell (x4), 0..124
    const bool has6 = (start < 5);

    if (c4 < ncell) {
        float gx[4], gy[4];
        #pragma unroll
        for (int j = 0; j < 4; ++j) {
            const int cell = cell0 + c4 + j;
            gx[j] = (float)(cell % GG);
            gy[j] = (float)(cell / GG);
        }

        // channels: start + 16k; k=0..4 always (ch<=79), k=5 iff start<5.
        // All 5-6 loads issued before any use (MLP within thread).
        f32x4 v0 = *(const f32x4*)(xb + (size_t)(start     ) * CELLS + c4);
        f32x4 v1 = *(const f32x4*)(xb + (size_t)(start + 16) * CELLS + c4);
        f32x4 v2 = *(const f32x4*)(xb + (size_t)(start + 32) * CELLS + c4);
        f32x4 v3 = *(const f32x4*)(xb + (size_t)(start + 48) * CELLS + c4);
        f32x4 v4 = *(const f32x4*)(xb + (size_t)(start + 64) * CELLS + c4);
        f32x4 v5 = v4;
        if (has6) v5 = *(const f32x4*)(xb + (size_t)(start + 80) * CELLS + c4);

        // channel 'start' (only one that can be special)
        {
            float r0 = v0.x, r1 = v0.y, r2 = v0.z, r3 = v0.w;
            if (start == 0) {
                r0 = (sigm(r0) + gx[0]) * STRIDEF;
                r1 = (sigm(r1) + gx[1]) * STRIDEF;
                r2 = (sigm(r2) + gx[2]) * STRIDEF;
                r3 = (sigm(r3) + gx[3]) * STRIDEF;
            } else if (start == 1) {
                r0 = (sigm(r0) + gy[0]) * STRIDEF;
                r1 = (sigm(r1) + gy[1]) * STRIDEF;
                r2 = (sigm(r2) + gy[2]) * STRIDEF;
                r3 = (sigm(r3) + gy[3]) * STRIDEF;
            } else if (start == 2) {
                r0 = __expf(r0) * aw; r1 = __expf(r1) * aw;
                r2 = __expf(r2) * aw; r3 = __expf(r3) * aw;
            } else if (start == 3) {
                r0 = __expf(r0) * ah; r1 = __expf(r1) * ah;
                r2 = __expf(r2) * ah; r3 = __expf(r3) * ah;
            } else {
                r0 = sigm(r0); r1 = sigm(r1); r2 = sigm(r2); r3 = sigm(r3);
            }
            lds[(c4    ) * NCH + start] = r0;
            lds[(c4 + 1) * NCH + start] = r1;
            lds[(c4 + 2) * NCH + start] = r2;
            lds[(c4 + 3) * NCH + start] = r3;
        }
        {
            const int ch = start + 16;
            lds[(c4    ) * NCH + ch] = sigm(v1.x);
            lds[(c4 + 1) * NCH + ch] = sigm(v1.y);
            lds[(c4 + 2) * NCH + ch] = sigm(v1.z);
            lds[(c4 + 3) * NCH + ch] = sigm(v1.w);
        }
        {
            const int ch = start + 32;
            lds[(c4    ) * NCH + ch] = sigm(v2.x);
            lds[(c4 + 1) * NCH + ch] = sigm(v2.y);
            lds[(c4 + 2) * NCH + ch] = sigm(v2.z);
            lds[(c4 + 3) * NCH + ch] = sigm(v2.w);
        }
        {
            const int ch = start + 48;
            lds[(c4    ) * NCH + ch] = sigm(v3.x);
            lds[(c4 + 1) * NCH + ch] = sigm(v3.y);
            lds[(c4 + 2) * NCH + ch] = sigm(v3.z);
            lds[(c4 + 3) * NCH + ch] = sigm(v3.w);
        }
        {
            const int ch = start + 64;
            lds[(c4    ) * NCH + ch] = sigm(v4.x);
            lds[(c4 + 1) * NCH + ch] = sigm(v4.y);
            lds[(c4 + 2) * NCH + ch] = sigm(v4.z);
            lds[(c4 + 3) * NCH + ch] = sigm(v4.w);
        }
        if (has6) {
            const int ch = start + 80;
            lds[(c4    ) * NCH + ch] = sigm(v5.x);
            lds[(c4 + 1) * NCH + ch] = sigm(v5.y);
            lds[(c4 + 2) * NCH + ch] = sigm(v5.z);
            lds[(c4 + 3) * NCH + ch] = sigm(v5.w);
        }
    }
    __syncthreads();

    // coalesced writeback: ncell*85 floats contiguous; wave writes 1KB/instr.
    // total4 = 2720 (full) or 340 (tail). Issue all ds_reads, then NT stores.
    float* ob = out + ((size_t)((b * NA + a) * CELLS + cell0)) * NCH;
    const int total4 = (ncell * NCH) >> 2;
    const f32x4* l4 = (const f32x4*)lds;
    f32x4* o4 = (f32x4*)ob;

    f32x4 t0 = {}, t1 = {}, t2 = {}, t3 = {}, t4 = {}, t5 = {};
    const int j0 = tid, j1 = tid + 512, j2 = tid + 1024;
    const int j3 = tid + 1536, j4 = tid + 2048, j5 = tid + 2560;
    if (j0 < total4) t0 = l4[j0];
    if (j1 < total4) t1 = l4[j1];
    if (j2 < total4) t2 = l4[j2];
    if (j3 < total4) t3 = l4[j3];
    if (j4 < total4) t4 = l4[j4];
    if (j5 < total4) t5 = l4[j5];
    if (j0 < total4) __builtin_nontemporal_store(t0, &o4[j0]);
    if (j1 < total4) __builtin_nontemporal_store(t1, &o4[j1]);
    if (j2 < total4) __builtin_nontemporal_store(t2, &o4[j2]);
    if (j3 < total4) __builtin_nontemporal_store(t3, &o4[j3]);
    if (j4 < total4) __builtin_nontemporal_store(t4, &o4[j4]);
    if (j5 < total4) __builtin_nontemporal_store(t5, &o4[j5]);
}

extern "C" void kernel_launch(void* const* d_in, const int* in_sizes, int n_in,
                              void* d_out, int out_size, void* d_ws, size_t ws_size,
                              hipStream_t stream) {
    const float* x = (const float*)d_in[0];
    float* out = (float*)d_out;

    dim3 grid(NTILES, NA, NB);      // 22 x 3 x 32 = 2112 blocks of 512
    yolo_decode<<<grid, 512, 0, stream>>>(x, out, (long long)out_size);
}

// Round 11
// 31.295 us; speedup vs baseline: 13.2748x; 1.0619x over previous
//
#include <hip/hip_runtime.h>
#include <math.h>

// YOLO box decode: x[B=32, A*(NC+5)=255, G=52, G=52] f32 ->
// out[B, A*G*G=8112, 85] f32  (+ trailing scalar 0 from the tuple return).
//
// R1: TILE 64 (7 blocks/CU), float4 reads, native exp.      47.2 -> 37.6 us
// R3/R4: unrolled 6-deep load/store phases (MLP), NT stores. 37.6 -> 35.7 us
// R5: TILE=52 FAILED (38.7): misaligned 208B segments, FETCH +22%.
// R6: wave-private 16-cell tiles FAILED (39.2): 64B read segments.
// R7/R8: 2-tile pipeline FAILED (415/165us): VGPR spills to scratch.
// R9: spill-free pipeline = R4+1% (35.3): compiler sank prefetch; latency
//     is NOT the binding constraint (Little's law: MLP is ample).
// R10: 512B read segments (block=512, TILE=128) WIN: 35.3 -> 33.2 us.
//     Stream geometry is the lever.
// R11: bijective XCD swizzle (nwg=2112 % 8 == 0): each XCD gets 264
//     contiguous work-ids = 12 full (b,a) panels = one sequential ~11MB
//     read sweep + ~11MB write sweep per XCD's L2/MC, instead of 8-way
//     interleaved fine streams. Kernel body identical to R10.

#define NB    32
#define NA    3
#define NCH   85
#define GG    52
#define CELLS (GG * GG)          // 2704
#define TILE  128                // cells per block
#define NTILES ((CELLS + TILE - 1) / TILE)   // 22 (21 full + tail of 16)
#define NWG   (NTILES * NA * NB) // 2112
#define STRIDEF 8.0f

typedef float f32x4 __attribute__((ext_vector_type(4)));

__device__ __forceinline__ float sigm(float v) {
    return __fdividef(1.0f, 1.0f + __expf(-v));
}

__global__ __launch_bounds__(512, 6) void yolo_decode(const float* __restrict__ x,
                                                      float* __restrict__ out,
                                                      long long out_size) {
    __shared__ __align__(16) float lds[TILE * NCH];   // 43.52 KB -> 3 blocks/CU

    // XCD-aware bijective swizzle: HW round-robins linear wg across 8 XCDs;
    // give XCD k the contiguous logical range [k*264, (k+1)*264).
    const int wg   = blockIdx.x;
    const int work = (wg & 7) * (NWG / 8) + (wg >> 3);
    const int tile = work % NTILES;
    const int ab   = work / NTILES;                   // 0..95
    const int a    = ab % NA;
    const int b    = ab / NA;

    const int cell0 = tile * TILE;
    const int ncell = min(TILE, CELLS - cell0);       // 128 or 16

    const int tid  = threadIdx.x;

    const float aw = (a == 0) ? 10.0f : (a == 1) ? 16.0f : 33.0f;
    const float ah = (a == 0) ? 13.0f : (a == 1) ? 30.0f : 23.0f;

    // fold the tuple's trailing scalar 0 into this kernel
    const long long MAIN = (long long)NB * NA * CELLS * NCH;
    if (work == 0 && tid == 0 && out_size > MAIN) {
        for (long long i = MAIN; i < out_size; ++i) out[i] = 0.0f;
    }

    const float* xb = x + ((size_t)(b * NA + a) * NCH) * CELLS + cell0;

    // 512 threads: 16 channel-groups x 32 cell-slots.
    // Each half-wave (32 lanes) reads one contiguous 512B segment per load.
    const int start = tid >> 5;                       // channel group 0..15
    const int c4    = (tid & 31) * 4;                 // local cell (x4), 0..124
    const bool has6 = (start < 5);

    if (c4 < ncell) {
        float gx[4], gy[4];
        #pragma unroll
        for (int j = 0; j < 4; ++j) {
            const int cell = cell0 + c4 + j;
            gx[j] = (float)(cell % GG);
            gy[j] = (float)(cell / GG);
        }

        // channels: start + 16k; k=0..4 always (ch<=79), k=5 iff start<5.
        // All 5-6 loads issued before any use (MLP within thread).
        f32x4 v0 = *(const f32x4*)(xb + (size_t)(start     ) * CELLS + c4);
        f32x4 v1 = *(const f32x4*)(xb + (size_t)(start + 16) * CELLS + c4);
        f32x4 v2 = *(const f32x4*)(xb + (size_t)(start + 32) * CELLS + c4);
        f32x4 v3 = *(const f32x4*)(xb + (size_t)(start + 48) * CELLS + c4);
        f32x4 v4 = *(const f32x4*)(xb + (size_t)(start + 64) * CELLS + c4);
        f32x4 v5 = v4;
        if (has6) v5 = *(const f32x4*)(xb + (size_t)(start + 80) * CELLS + c4);

        // channel 'start' (only one that can be special)
        {
            float r0 = v0.x, r1 = v0.y, r2 = v0.z, r3 = v0.w;
            if (start == 0) {
                r0 = (sigm(r0) + gx[0]) * STRIDEF;
                r1 = (sigm(r1) + gx[1]) * STRIDEF;
                r2 = (sigm(r2) + gx[2]) * STRIDEF;
                r3 = (sigm(r3) + gx[3]) * STRIDEF;
            } else if (start == 1) {
                r0 = (sigm(r0) + gy[0]) * STRIDEF;
                r1 = (sigm(r1) + gy[1]) * STRIDEF;
                r2 = (sigm(r2) + gy[2]) * STRIDEF;
                r3 = (sigm(r3) + gy[3]) * STRIDEF;
            } else if (start == 2) {
                r0 = __expf(r0) * aw; r1 = __expf(r1) * aw;
                r2 = __expf(r2) * aw; r3 = __expf(r3) * aw;
            } else if (start == 3) {
                r0 = __expf(r0) * ah; r1 = __expf(r1) * ah;
                r2 = __expf(r2) * ah; r3 = __expf(r3) * ah;
            } else {
                r0 = sigm(r0); r1 = sigm(r1); r2 = sigm(r2); r3 = sigm(r3);
            }
            lds[(c4    ) * NCH + start] = r0;
            lds[(c4 + 1) * NCH + start] = r1;
            lds[(c4 + 2) * NCH + start] = r2;
            lds[(c4 + 3) * NCH + start] = r3;
        }
        {
            const int ch = start + 16;
            lds[(c4    ) * NCH + ch] = sigm(v1.x);
            lds[(c4 + 1) * NCH + ch] = sigm(v1.y);
            lds[(c4 + 2) * NCH + ch] = sigm(v1.z);
            lds[(c4 + 3) * NCH + ch] = sigm(v1.w);
        }
        {
            const int ch = start + 32;
            lds[(c4    ) * NCH + ch] = sigm(v2.x);
            lds[(c4 + 1) * NCH + ch] = sigm(v2.y);
            lds[(c4 + 2) * NCH + ch] = sigm(v2.z);
            lds[(c4 + 3) * NCH + ch] = sigm(v2.w);
        }
        {
            const int ch = start + 48;
            lds[(c4    ) * NCH + ch] = sigm(v3.x);
            lds[(c4 + 1) * NCH + ch] = sigm(v3.y);
            lds[(c4 + 2) * NCH + ch] = sigm(v3.z);
            lds[(c4 + 3) * NCH + ch] = sigm(v3.w);
        }
        {
            const int ch = start + 64;
            lds[(c4    ) * NCH + ch] = sigm(v4.x);
            lds[(c4 + 1) * NCH + ch] = sigm(v4.y);
            lds[(c4 + 2) * NCH + ch] = sigm(v4.z);
            lds[(c4 + 3) * NCH + ch] = sigm(v4.w);
        }
        if (has6) {
            const int ch = start + 80;
            lds[(c4    ) * NCH + ch] = sigm(v5.x);
            lds[(c4 + 1) * NCH + ch] = sigm(v5.y);
            lds[(c4 + 2) * NCH + ch] = sigm(v5.z);
            lds[(c4 + 3) * NCH + ch] = sigm(v5.w);
        }
    }
    __syncthreads();

    // coalesced writeback: ncell*85 floats contiguous; wave writes 1KB/instr.
    // total4 = 2720 (full) or 340 (tail). Issue all ds_reads, then NT stores.
    float* ob = out + ((size_t)((b * NA + a) * CELLS + cell0)) * NCH;
    const int total4 = (ncell * NCH) >> 2;
    const f32x4* l4 = (const f32x4*)lds;
    f32x4* o4 = (f32x4*)ob;

    f32x4 t0 = {}, t1 = {}, t2 = {}, t3 = {}, t4 = {}, t5 = {};
    const int j0 = tid, j1 = tid + 512, j2 = tid + 1024;
    const int j3 = tid + 1536, j4 = tid + 2048, j5 = tid + 2560;
    if (j0 < total4) t0 = l4[j0];
    if (j1 < total4) t1 = l4[j1];
    if (j2 < total4) t2 = l4[j2];
    if (j3 < total4) t3 = l4[j3];
    if (j4 < total4) t4 = l4[j4];
    if (j5 < total4) t5 = l4[j5];
    if (j0 < total4) __builtin_nontemporal_store(t0, &o4[j0]);
    if (j1 < total4) __builtin_nontemporal_store(t1, &o4[j1]);
    if (j2 < total4) __builtin_nontemporal_store(t2, &o4[j2]);
    if (j3 < total4) __builtin_nontemporal_store(t3, &o4[j3]);
    if (j4 < total4) __builtin_nontemporal_store(t4, &o4[j4]);
    if (j5 < total4) __builtin_nontemporal_store(t5, &o4[j5]);
}

extern "C" void kernel_launch(void* const* d_in, const int* in_sizes, int n_in,
                              void* d_out, int out_size, void* d_ws, size_t ws_size,
                              hipStream_t stream) {
    const float* x = (const float*)d_in[0];
    float* out = (float*)d_out;

    yolo_decode<<<dim3(NWG), 512, 0, stream>>>(x, out, (long long)out_size);
}